// Round 7
// baseline (35.932 us; speedup 1.0000x reference)
//
#include <hip/hip_runtime.h>
#include <hip/hip_bf16.h>

// DCN cross stack collapsed (validated rounds 1-6):
//   u_k = x0.w_k, e_k = d_k.w_k (d_k = sum_{j<k} b_j), c_{k+1} = c_k(1+u_k)+e_k
//   out[t] = c_4 * (x0 . Wout[:,t]) + d_4.Wout[:,t] + bo[t]
// 12 dots/row == GEMM X[65536x512] @ Wcat[512x12pad16] via mfma_f32_16x16x32_bf16
// with split-x 2-term product (AhB + AlB), B in bf16.
//
// Round-7: single kernel, overhead-minimized.
//  - x prefetch (depth 6) ISSUED FIRST: HBM stream starts at cycle ~0; the
//    Bh build + barrier absorb the first-load latency.
//  - cooperative Bh build into LDS (16 KB, one barrier) — B table in LDS
//    frees 64 VGPRs vs round 6's register table.
//  - e/g constants moved to the EPILOGUE, computed redundantly per wave from
//    L2-hot weights -> zero preamble cost, no second kernel, no ws, no gap.

typedef float v4f __attribute__((ext_vector_type(4)));
typedef float f32x4 __attribute__((ext_vector_type(4)));
typedef short s16x8 __attribute__((ext_vector_type(8)));

__device__ __forceinline__ short f2bf(float v) {          // RTNE fp32->bf16
  return __builtin_bit_cast(short, __float2bfloat16(v));
}
__device__ __forceinline__ float bf2f(short s) {
  return __uint_as_float(((unsigned)(unsigned short)s) << 16);
}

template<int CTRL>
__device__ __forceinline__ float dpp_add(float v) {
  int t = __builtin_amdgcn_update_dpp(0, __float_as_int(v), CTRL, 0xF, 0xF, true);
  return v + __int_as_float(t);
}
__device__ __forceinline__ float wave_reduce(float v) {   // total in lane 63
  v = dpp_add<0x111>(v); v = dpp_add<0x112>(v); v = dpp_add<0x114>(v);
  v = dpp_add<0x118>(v); v = dpp_add<0x142>(v); v = dpp_add<0x143>(v);
  return v;
}

__global__ __launch_bounds__(256, 4) void cross_one(
    const float* __restrict__ x, const float* __restrict__ cw,
    const float* __restrict__ cb, const float* __restrict__ Wo,
    const float* __restrict__ bo, float* __restrict__ out)
{
  __shared__ s16x8 Bh[16][64];     // 16 KB B-fragment table (bf16)
  __shared__ float ct[4][16][17];  // 4.25 KB epilogue transpose scratch

  const int tid = threadIdx.x, lane = tid & 63, wv = tid >> 6;
  const int row0 = (blockIdx.x << 6) + (wv << 4);
  const float* xr = x + (size_t)(row0 + (lane & 15)) * 512 + ((lane >> 4) << 3);

  // ---- 1) start the x stream immediately: depth-6 register prefetch -------
  v4f xa[6], xb[6];
  #pragma unroll
  for (int p = 0; p < 6; ++p) {
    xa[p] = *(const v4f*)(xr + p * 32);
    xb[p] = *(const v4f*)(xr + p * 32 + 4);
  }

  // ---- 2) cooperative Bh build (validated round 5), overlaps x latency ----
  #pragma unroll
  for (int slot = 0; slot < 4; ++slot) {
    const int s = (tid >> 6) + (slot << 2);
    const int l = tid & 63;
    const int c = l & 15, k0 = s * 32 + ((l >> 4) << 3);
    float f[8];
    if (c < 4) {
      v4f a = *(const v4f*)(cw + c * 512 + k0);
      v4f b = *(const v4f*)(cw + c * 512 + k0 + 4);
      #pragma unroll
      for (int j = 0; j < 4; ++j) { f[j] = a[j]; f[4 + j] = b[j]; }
    } else if (c < 12) {
      #pragma unroll
      for (int j = 0; j < 8; ++j) f[j] = Wo[(k0 + j) * 8 + (c - 4)];
    } else {
      #pragma unroll
      for (int j = 0; j < 8; ++j) f[j] = 0.f;
    }
    s16x8 h;
    #pragma unroll
    for (int j = 0; j < 8; ++j) h[j] = f2bf(f[j]);
    Bh[s][l] = h;
  }
  __syncthreads();

  // ---- 3) main loop: 16 K-steps, 1 ds_read_b128 + 2 dwordx4 + 2 MFMA ------
  f32x4 acc = {0.f, 0.f, 0.f, 0.f};
  #pragma unroll
  for (int s = 0; s < 16; ++s) {
    const int cur = s % 6;                  // s is compile-time (full unroll)
    const v4f pa = xa[cur], pb = xb[cur];
    if (s + 6 < 16) {
      xa[cur] = *(const v4f*)(xr + (s + 6) * 32);
      xb[cur] = *(const v4f*)(xr + (s + 6) * 32 + 4);
    }
    const s16x8 bh = Bh[s][lane];
    s16x8 ah, al;
    #pragma unroll
    for (int j = 0; j < 4; ++j) {
      ah[j]     = f2bf(pa[j]); al[j]     = f2bf(pa[j] - bf2f(ah[j]));
      ah[4 + j] = f2bf(pb[j]); al[4 + j] = f2bf(pb[j] - bf2f(ah[4 + j]));
    }
    acc = __builtin_amdgcn_mfma_f32_16x16x32_bf16(ah, bh, acc, 0, 0, 0);
    acc = __builtin_amdgcn_mfma_f32_16x16x32_bf16(al, bh, acc, 0, 0, 0);
  }

  // ---- 4) epilogue: constants (redundant per wave, L2-hot weights) --------
  float e1, e2, e3, gg[8];
  {
    const int f0 = lane << 3;
    v4f d0a = *(const v4f*)(cb + f0),        d0b = *(const v4f*)(cb + f0 + 4);
    v4f c1a = *(const v4f*)(cb + 512 + f0),  c1b = *(const v4f*)(cb + 512 + f0 + 4);
    v4f c2a = *(const v4f*)(cb + 1024 + f0), c2b = *(const v4f*)(cb + 1024 + f0 + 4);
    v4f c3a = *(const v4f*)(cb + 1536 + f0), c3b = *(const v4f*)(cb + 1536 + f0 + 4);
    v4f w1a = *(const v4f*)(cw + 512 + f0),  w1b = *(const v4f*)(cw + 512 + f0 + 4);
    v4f w2a = *(const v4f*)(cw + 1024 + f0), w2b = *(const v4f*)(cw + 1024 + f0 + 4);
    v4f w3a = *(const v4f*)(cw + 1536 + f0), w3b = *(const v4f*)(cw + 1536 + f0 + 4);
    float e1p = 0.f, e2p = 0.f, e3p = 0.f;
    v4f dA = d0a, dB = d0b;
    #pragma unroll
    for (int e = 0; e < 4; ++e) e1p += dA[e] * w1a[e] + dB[e] * w1b[e];
    dA += c1a; dB += c1b;
    #pragma unroll
    for (int e = 0; e < 4; ++e) e2p += dA[e] * w2a[e] + dB[e] * w2b[e];
    dA += c2a; dB += c2b;
    #pragma unroll
    for (int e = 0; e < 4; ++e) e3p += dA[e] * w3a[e] + dB[e] * w3b[e];
    dA += c3a; dB += c3b;
    float gp[8] = {0.f,0.f,0.f,0.f,0.f,0.f,0.f,0.f};
    #pragma unroll
    for (int e = 0; e < 4; ++e) {
      const float* wra = Wo + (f0 + e) * 8;
      const float* wrb = Wo + (f0 + 4 + e) * 8;
      #pragma unroll
      for (int t = 0; t < 8; ++t) gp[t] += dA[e] * wra[t] + dB[e] * wrb[t];
    }
    e1p = wave_reduce(e1p); e2p = wave_reduce(e2p); e3p = wave_reduce(e3p);
    #pragma unroll
    for (int t = 0; t < 8; ++t) gp[t] = wave_reduce(gp[t]);
    e1 = __shfl(e1p, 63); e2 = __shfl(e2p, 63); e3 = __shfl(e3p, 63);
    #pragma unroll
    for (int t = 0; t < 8; ++t) gg[t] = __shfl(gp[t], 63) + bo[t];
  }

  // ---- 5) transpose C via wave-private LDS, recurrence, store -------------
  #pragma unroll
  for (int j = 0; j < 4; ++j)
    ct[wv][((lane >> 4) << 2) + j][lane & 15] = acc[j];
  __builtin_amdgcn_s_waitcnt(0);  // wave-private tile: drain lgkm within wave
  if (lane < 16) {
    const float u0 = ct[wv][lane][0], u1 = ct[wv][lane][1];
    const float u2 = ct[wv][lane][2], u3 = ct[wv][lane][3];
    const float cc1 = 1.f + u0;
    const float cc2 = fmaf(cc1, u1, cc1) + e1;
    const float cc3 = fmaf(cc2, u2, cc2) + e2;
    const float cc4 = fmaf(cc3, u3, cc3) + e3;
    v4f o0, o1;
    #pragma unroll
    for (int t = 0; t < 4; ++t) {
      o0[t] = fmaf(cc4, ct[wv][lane][4 + t], gg[t]);
      o1[t] = fmaf(cc4, ct[wv][lane][8 + t], gg[4 + t]);
    }
    float* op = out + (size_t)(row0 + lane) * 8;
    *(v4f*)(op)     = o0;
    *(v4f*)(op + 4) = o1;
  }
}

extern "C" void kernel_launch(void* const* d_in, const int* in_sizes, int n_in,
                              void* d_out, int out_size, void* d_ws, size_t ws_size,
                              hipStream_t stream) {
  const float* x  = (const float*)d_in[0];
  const float* cw = (const float*)d_in[1];
  const float* cb = (const float*)d_in[2];
  const float* Wo = (const float*)d_in[3];
  const float* bo = (const float*)d_in[4];
  float* out = (float*)d_out;
  const int B = in_sizes[0] / 512;          // 65536
  hipLaunchKernelGGL(cross_one, dim3(B >> 6), dim3(256), 0, stream,
                     x, cw, cb, Wo, bo, out);
}

// Round 8
// 30.573 us; speedup vs baseline: 1.1753x; 1.1753x over previous
//
#include <hip/hip_runtime.h>
#include <hip/hip_bf16.h>

// DCN cross stack collapsed (validated rounds 1-7):
//   u_k = x0.w_k, e_k = d_k.w_k (d_k = sum_{j<k} b_j), c_{k+1} = c_k(1+u_k)+e_k
//   out[t] = c_4 * (x0 . Wout[:,t]) + d_4.Wout[:,t] + bo[t]
// 12 dots/row == GEMM X[65536x512] @ Wcat[512x12pad16] via mfma_f32_16x16x32_bf16
// with split-x 2-term product (AhB + AlB), B in bf16.
//
// Round-8: fix the x-stream memory pattern. Previous rounds loaded 16B/lane
// across 16 scattered rows -> half-line utilization per instruction + L1
// thrash (lines fetched ~2x from L2). Now x is staged via global_load_lds
// where each instruction covers 8 rows x 128B = every 64B line fully consumed
// by one instruction (the pattern fillBuffer streams at 7.2 TB/s with).
// Wave-private double-buffered 2KB slabs, counted vmcnt(2) (never 0 in-loop),
// no barriers in the main loop. MFMA-fragment reformat happens in LDS with a
// chunk-XOR swizzle applied on BOTH sides (pre-permuted global source +
// swizzled ds_read_b128) -> <=2-way bank aliasing (free).

typedef float v4f __attribute__((ext_vector_type(4)));
typedef float f32x4 __attribute__((ext_vector_type(4)));
typedef short s16x8 __attribute__((ext_vector_type(8)));

__device__ __forceinline__ short f2bf(float v) {          // RTNE fp32->bf16
  return __builtin_bit_cast(short, __float2bfloat16(v));
}
__device__ __forceinline__ float bf2f(short s) {
  return __uint_as_float(((unsigned)(unsigned short)s) << 16);
}

template<int CTRL>
__device__ __forceinline__ float dpp_add(float v) {
  int t = __builtin_amdgcn_update_dpp(0, __float_as_int(v), CTRL, 0xF, 0xF, true);
  return v + __int_as_float(t);
}
__device__ __forceinline__ float wave_reduce(float v) {   // total in lane 63
  v = dpp_add<0x111>(v); v = dpp_add<0x112>(v); v = dpp_add<0x114>(v);
  v = dpp_add<0x118>(v); v = dpp_add<0x142>(v); v = dpp_add<0x143>(v);
  return v;
}

__global__ __launch_bounds__(256, 4) void cross_glds(
    const float* __restrict__ x, const float* __restrict__ cw,
    const float* __restrict__ cb, const float* __restrict__ Wo,
    const float* __restrict__ bo, float* __restrict__ out)
{
  __shared__ s16x8 Bh[16][64];       // 16 KB   B-fragment table (bf16)
  __shared__ float slab[2][4][512];  // 16 KB   2 buf x 4 waves x 2KB x-slab
  __shared__ float ct[4][16][17];    // 4.25 KB epilogue transpose scratch
  __shared__ float egs[12];          // e1,e2,e3, g[0..7]

  const int tid = threadIdx.x, lane = tid & 63, wv = tid >> 6;
  const int row0 = (blockIdx.x << 6) + (wv << 4);

  // ---- staging source: lane covers row0+(lane>>3), permuted 16B chunk -----
  // LDS slot (row,chunk c) receives global chunk c^(row&7); each instruction
  // covers 8 rows x 128B -> all touched 64B lines fully used.
  const int prow = lane >> 3;                          // 0..7
  const int pchk = (lane & 7) ^ prow;                  // permuted chunk
  const float* srcA = x + (size_t)(row0 + prow) * 512 + (pchk << 2);
  const float* srcB = srcA + 8 * 512;                  // rows +8 (same row&7)

#define GLDS(srcp, dstp)                                                     \
  __builtin_amdgcn_global_load_lds(                                          \
      (const __attribute__((address_space(1))) float*)(srcp),                \
      (__attribute__((address_space(3))) float*)(dstp), 16, 0, 0)
#define STAGE(s, b) do {                                                     \
    GLDS(srcA + (s) * 32, &slab[b][wv][0]);                                  \
    GLDS(srcB + (s) * 32, &slab[b][wv][256]);                                \
  } while (0)
#define WAITV(n) do { asm volatile("s_waitcnt vmcnt(" #n ")" ::: "memory");  \
                      __builtin_amdgcn_sched_barrier(0); } while (0)
#define WAITL()  do { asm volatile("s_waitcnt lgkmcnt(0)" ::: "memory");     \
                      __builtin_amdgcn_sched_barrier(0); } while (0)

  // ---- 1) start the x stream immediately (slabs 0 and 1) ------------------
  STAGE(0, 0);
  STAGE(1, 1);

  // ---- 2) cooperative Bh build (validated R5) -----------------------------
  for (int slot = tid; slot < 1024; slot += 256) {
    const int s = slot >> 6, l = slot & 63;
    const int c = l & 15, k0 = s * 32 + ((l >> 4) << 3);
    float f[8];
    if (c < 4) {
      v4f a = *(const v4f*)(cw + c * 512 + k0);
      v4f b = *(const v4f*)(cw + c * 512 + k0 + 4);
      #pragma unroll
      for (int j = 0; j < 4; ++j) { f[j] = a[j]; f[4 + j] = b[j]; }
    } else if (c < 12) {
      #pragma unroll
      for (int j = 0; j < 8; ++j) f[j] = Wo[(k0 + j) * 8 + (c - 4)];
    } else {
      #pragma unroll
      for (int j = 0; j < 8; ++j) f[j] = 0.f;
    }
    s16x8 h;
    #pragma unroll
    for (int j = 0; j < 8; ++j) h[j] = f2bf(f[j]);
    Bh[s][l] = h;
  }

  // ---- 3) wave 0: exact fp32 constants (validated R5) ---------------------
  if (wv == 0) {
    const int f0 = lane << 3;
    v4f d0a = *(const v4f*)(cb + f0),        d0b = *(const v4f*)(cb + f0 + 4);
    v4f c1a = *(const v4f*)(cb + 512 + f0),  c1b = *(const v4f*)(cb + 512 + f0 + 4);
    v4f c2a = *(const v4f*)(cb + 1024 + f0), c2b = *(const v4f*)(cb + 1024 + f0 + 4);
    v4f c3a = *(const v4f*)(cb + 1536 + f0), c3b = *(const v4f*)(cb + 1536 + f0 + 4);
    v4f w1a = *(const v4f*)(cw + 512 + f0),  w1b = *(const v4f*)(cw + 512 + f0 + 4);
    v4f w2a = *(const v4f*)(cw + 1024 + f0), w2b = *(const v4f*)(cw + 1024 + f0 + 4);
    v4f w3a = *(const v4f*)(cw + 1536 + f0), w3b = *(const v4f*)(cw + 1536 + f0 + 4);
    float e1p = 0.f, e2p = 0.f, e3p = 0.f;
    v4f dA = d0a, dB = d0b;
    #pragma unroll
    for (int e = 0; e < 4; ++e) e1p += dA[e] * w1a[e] + dB[e] * w1b[e];
    dA += c1a; dB += c1b;
    #pragma unroll
    for (int e = 0; e < 4; ++e) e2p += dA[e] * w2a[e] + dB[e] * w2b[e];
    dA += c2a; dB += c2b;
    #pragma unroll
    for (int e = 0; e < 4; ++e) e3p += dA[e] * w3a[e] + dB[e] * w3b[e];
    dA += c3a; dB += c3b;
    float gp[8] = {0.f,0.f,0.f,0.f,0.f,0.f,0.f,0.f};
    #pragma unroll
    for (int e = 0; e < 4; ++e) {
      const float* wra = Wo + (f0 + e) * 8;
      const float* wrb = Wo + (f0 + 4 + e) * 8;
      #pragma unroll
      for (int t = 0; t < 8; ++t) gp[t] += dA[e] * wra[t] + dB[e] * wrb[t];
    }
    e1p = wave_reduce(e1p); e2p = wave_reduce(e2p); e3p = wave_reduce(e3p);
    #pragma unroll
    for (int t = 0; t < 8; ++t) gp[t] = wave_reduce(gp[t]);
    if (lane == 63) {
      egs[0] = e1p; egs[1] = e2p; egs[2] = e3p;
      #pragma unroll
      for (int t = 0; t < 8; ++t) egs[3 + t] = gp[t] + bo[t];
    }
  }
  __syncthreads();

  // ---- 4) main loop: wave-private slabs, counted vmcnt, swizzled reads ----
  // lane l consumes row l&15, chunks g=(l>>4)*2 and g+1; stored at slots
  // g^(row&7) and (g+1)^(row&7) -> <=2-way bank aliasing on ds_read_b128.
  const int rrow = lane & 15;
  const int g    = (lane >> 4) << 1;
  const int ro   = (rrow << 5) + ((g ^ (rrow & 7)) << 2);        // float offs
  const int ro1  = (rrow << 5) + (((g + 1) ^ (rrow & 7)) << 2);
  const float* rp0 = &slab[0][wv][0];
  const float* rp1 = &slab[1][wv][0];

  f32x4 acc = {0.f, 0.f, 0.f, 0.f};
  #pragma unroll
  for (int s = 0; s < 16; ++s) {
    if (s < 15) { WAITV(2); } else { WAITV(0); }   // slab s landed in LDS
    const float* rp = (s & 1) ? rp1 : rp0;
    const v4f pa = *(const v4f*)(rp + ro);
    const v4f pb = *(const v4f*)(rp + ro1);
    WAITL();                                       // reads retired -> reuse ok
    if (s + 2 < 16) STAGE(s + 2, s & 1);
    const s16x8 bh = Bh[s][lane];
    s16x8 ah, al;
    #pragma unroll
    for (int j = 0; j < 4; ++j) {
      ah[j]     = f2bf(pa[j]); al[j]     = f2bf(pa[j] - bf2f(ah[j]));
      ah[4 + j] = f2bf(pb[j]); al[4 + j] = f2bf(pb[j] - bf2f(ah[4 + j]));
    }
    acc = __builtin_amdgcn_mfma_f32_16x16x32_bf16(ah, bh, acc, 0, 0, 0);
    acc = __builtin_amdgcn_mfma_f32_16x16x32_bf16(al, bh, acc, 0, 0, 0);
  }

  // ---- 5) epilogue: transpose C, recurrence, store ------------------------
  const float e1 = egs[0], e2 = egs[1], e3 = egs[2];
  float gg[8];
  #pragma unroll
  for (int t = 0; t < 8; ++t) gg[t] = egs[3 + t];

  #pragma unroll
  for (int j = 0; j < 4; ++j)
    ct[wv][((lane >> 4) << 2) + j][lane & 15] = acc[j];
  WAITL();                                         // wave-private tile drain
  if (lane < 16) {
    const float u0 = ct[wv][lane][0], u1 = ct[wv][lane][1];
    const float u2 = ct[wv][lane][2], u3 = ct[wv][lane][3];
    const float cc1 = 1.f + u0;
    const float cc2 = fmaf(cc1, u1, cc1) + e1;
    const float cc3 = fmaf(cc2, u2, cc2) + e2;
    const float cc4 = fmaf(cc3, u3, cc3) + e3;
    v4f o0, o1;
    #pragma unroll
    for (int t = 0; t < 4; ++t) {
      o0[t] = fmaf(cc4, ct[wv][lane][4 + t], gg[t]);
      o1[t] = fmaf(cc4, ct[wv][lane][8 + t], gg[4 + t]);
    }
    float* op = out + (size_t)(row0 + lane) * 8;
    *(v4f*)(op)     = o0;
    *(v4f*)(op + 4) = o1;
  }
#undef GLDS
#undef STAGE
#undef WAITV
#undef WAITL
}

extern "C" void kernel_launch(void* const* d_in, const int* in_sizes, int n_in,
                              void* d_out, int out_size, void* d_ws, size_t ws_size,
                              hipStream_t stream) {
  const float* x  = (const float*)d_in[0];
  const float* cw = (const float*)d_in[1];
  const float* cb = (const float*)d_in[2];
  const float* Wo = (const float*)d_in[3];
  const float* bo = (const float*)d_in[4];
  float* out = (float*)d_out;
  const int B = in_sizes[0] / 512;          // 65536
  hipLaunchKernelGGL(cross_glds, dim3(B >> 6), dim3(256), 0, stream,
                     x, cw, cb, Wo, bo, out);
}